// Round 1
// 35360.400 us; speedup vs baseline: 1.0003x; 1.0003x over previous
//
#include <hip/hip_runtime.h>
#include <math.h>

// LSTMNN: T=1024, B=64, I=128, H=512, L=2, fp32. Persistent 256 WG x 512 thr.
// Round 5: de-contend the coherence point (theory: 29us/step of the 34.5us
// step is MALL serialization, only 5.4us is VALU work).
//   (a) Barrier: padded monotonic 2-level barrier. Per-group arrival
//       counters and per-group release flags each on their own 256B line;
//       generation is a local register (no pre-read); counters never reset
//       (monotonic) so there is no reset/release ordering hazard.
//   (b) Activation reads: plain cached loads (L1/L2 serve the 256x
//       broadcast at 34.5TB/s aggregate) instead of sc0sc1 L3-bypass.
//       Correctness: all global data stores remain sc0sc1 write-through
//       (L2 never dirty for act lines; buffer_inv preserves dirty lines
//       anyway) + one agent-acquire fence (buffer_inv) per step after the
//       grid barrier invalidates stale L1/L2 copies.
//   (c) h1T buffer eliminated: out_block gathers its h1 column (512
//       strided dwords, L2-hot from the gemv that just streamed h1) into
//       LDS once. Kills 16MB/step of 32x-redundant sc reads and ~2MB/step
//       of scattered 4B write-through RMW (the FETCH/WRITE inflation).

namespace {
constexpr int T_STEPS = 1024;
constexpr int B = 64;
constexpr int I_DIM = 128;
constexpr int H = 512;
constexpr int NBLK = 256;
constexpr int NTHR = 512;
constexpr int HB = H * B;  // 32768
constexpr int P = 20;      // padded chunk dim for LDS weights

// ws layout (floats)
constexpr int OFF_INP  = 0;                  // [2][512][64] inp^T parity
constexpr int OFF_H0   = OFF_INP + 2 * HB;   // [2][512][64] h0^T parity
constexpr int OFF_H1   = OFF_H0 + 2 * HB;    // [2][512][64] h1^T parity (k-major)
constexpr int OFF_BSUM = OFF_H1 + 2 * HB;    // [2][2048] b_ih+b_hh
constexpr int OFF_BAR  = OFF_BSUM + 2 * 4 * H;  // barrier state, 256B-aligned
// barrier slots, stride 64 uints (256B): [0..15] group arrivals,
// [16] master, [17..32] per-group release flags, [33] poison
constexpr int BAR_SLOTS = 34;
constexpr int BAR_UINTS = BAR_SLOTS * 64;  // 2176
}  // namespace

typedef float f32x4 __attribute__((ext_vector_type(4)));

// coherent write-through store (sc0 sc1): data lands at the coherence
// point, no dirty L2 copy anywhere.
__device__ __forceinline__ void coh_store1(float* p, float v) {
  asm volatile("global_store_dword %0, %1, off sc0 sc1" ::"v"(p), "v"(v)
               : "memory");
}

__global__ __launch_bounds__(NTHR) void init_ws_kernel(
    float* __restrict__ ws, const float* __restrict__ b_ih,
    const float* __restrict__ b_hh) {
  int idx = blockIdx.x * blockDim.x + threadIdx.x;
  for (int f = idx; f < OFF_BSUM; f += NBLK * NTHR) coh_store1(ws + f, 0.f);
  if (idx < 2 * 4 * H) coh_store1(ws + OFF_BSUM + idx, b_ih[idx] + b_hh[idx]);
  if (idx < BAR_UINTS) coh_store1(ws + OFF_BAR + idx, 0.f);  // bits == 0u
}

__device__ __forceinline__ float sigm(float x) {
  return 1.f / (1.f + __expf(-x));
}
__device__ __forceinline__ float tanh_fast(float x) {
  float e = __expf(-2.f * fabsf(x));
  float t = (1.f - e) / (1.f + e);
  return x < 0.f ? -t : t;
}

__global__ __launch_bounds__(NTHR, 2) void lstm_kernel(
    const float* __restrict__ x, const float* __restrict__ w_in,
    const float* __restrict__ b_in, const float* __restrict__ w_ih,
    const float* __restrict__ w_hh, const float* __restrict__ w_out,
    const float* __restrict__ b_out, float* __restrict__ ws,
    float* __restrict__ out) {
  __shared__ float s_w[2 * 8 * 64 * P];  // 80 KB persistent gate weights
  __shared__ float s_red[4096];          // 16 KB reduction scratch
  __shared__ float s_g[512];             // 2 KB gate pre-activations
  __shared__ float s_h1[512];            // 2 KB gathered h1 column (out)

  const int tid = threadIdx.x;
  const int wg = blockIdx.x;
  unsigned* const bar = reinterpret_cast<unsigned*>(ws + OFF_BAR);

  // ---- persistent weight load: s_w[((l*8+r)*64+s)*P + c] = W[l][grow][k],
  //      k = c*64 + s (K-concat: k<512 -> w_ih, else w_hh) ----
#pragma unroll
  for (int i = 0; i < 8; ++i) {
    int idx = i * 512 + tid;  // float4 unit 0..4095
    int l = idx >> 11;
    int rem = idx & 2047;
    int r = rem >> 8;
    int k0 = (rem & 255) * 4;
    int grow = (r >> 1) * 512 + wg * 2 + (r & 1);
    const float* srcp =
        (k0 < 512) ? (w_ih + ((size_t)l * 4 * H + grow) * H + k0)
                   : (w_hh + ((size_t)l * 4 * H + grow) * H + (k0 - 512));
    float4 v = *reinterpret_cast<const float4*>(srcp);
    float arr[4] = {v.x, v.y, v.z, v.w};
#pragma unroll
    for (int j = 0; j < 4; ++j) {
      int k = k0 + j;
      int c = k >> 6, ss = k & 63;
      s_w[((l * 8 + r) * 64 + ss) * P + c] = arr[j];
    }
  }
  __syncthreads();

  // ---- grid barrier: padded monotonic 2-level, per-group release flags.
  //      After release: one agent-acquire fence (buffer_inv) so the plain
  //      cached activation loads of the next step see fresh data. ----
  unsigned bar_gen = 0;
  auto gridbar = [&]() {
    ++bar_gen;
    __syncthreads();  // per-wave vmcnt drain: all sc0sc1 data stores are at
                      // the coherence point before the leader signs in
    if (tid == 0) {
      if (__hip_atomic_load(bar + 33 * 64, __ATOMIC_RELAXED,
                            __HIP_MEMORY_SCOPE_AGENT) == 0u) {
        const unsigned grp = (unsigned)wg & 15u;
        unsigned prev = __hip_atomic_fetch_add(
            bar + grp * 64, 1u, __ATOMIC_RELAXED, __HIP_MEMORY_SCOPE_AGENT);
        bool done = false;
        if ((prev & 15u) == 15u) {  // last of group (monotonic count)
          unsigned mprev = __hip_atomic_fetch_add(
              bar + 16 * 64, 1u, __ATOMIC_RELAXED, __HIP_MEMORY_SCOPE_AGENT);
          if ((mprev & 15u) == 15u) {  // last group: release everyone
#pragma unroll
            for (int g2 = 0; g2 < 16; ++g2)
              __hip_atomic_store(bar + (17 + g2) * 64, bar_gen,
                                 __ATOMIC_RELAXED, __HIP_MEMORY_SCOPE_AGENT);
            done = true;
          }
        }
        if (!done) {
          unsigned spin = 0;
          while (__hip_atomic_load(bar + (17 + grp) * 64, __ATOMIC_RELAXED,
                                   __HIP_MEMORY_SCOPE_AGENT) < bar_gen) {
            __builtin_amdgcn_s_sleep(1);
            if ((++spin & 1023u) == 0u) {  // rare-path checks off hot loop
              if (__hip_atomic_load(bar + 33 * 64, __ATOMIC_RELAXED,
                                    __HIP_MEMORY_SCOPE_AGENT) != 0u)
                break;
              if (spin > (1u << 20)) {  // failsafe: fast-fail, don't hang
                __hip_atomic_store(bar + 33 * 64, 1u, __ATOMIC_RELAXED,
                                   __HIP_MEMORY_SCOPE_AGENT);
                break;
              }
            }
          }
        }
      }
    }
    __syncthreads();
    // invalidate stale clean L1/L2 lines (dirty lines are preserved by HW);
    // every wave fences so its own subsequent loads are ordered behind it.
    __builtin_amdgcn_fence(__ATOMIC_ACQUIRE, "agent");
  };

  // ---- out(tt): gather h1 column b from k-major parity buf (L2-hot from
  //      the gemv that just streamed it) into LDS once, then reduce ----
  auto out_block = [&](int tt, int parb) {
    const int b = wg >> 2;
    s_h1[tid] = ws[OFF_H1 + (size_t)parb * HB + tid * 64 + b];  // cached
    __syncthreads();
    const int o = tid & 31, ks = tid >> 5;  // ks 0..15, 32 k each
    const int i = (wg & 3) * 32 + o;
    const float* wrow = w_out + (size_t)i * H + ks * 32;
    const float* hl = s_h1 + ks * 32;  // same addr across o: LDS broadcast
    float part = 0.f;
#pragma unroll
    for (int k4 = 0; k4 < 8; ++k4) {
      float4 wv = *reinterpret_cast<const float4*>(wrow + k4 * 4);
      part += wv.x * hl[k4 * 4 + 0] + wv.y * hl[k4 * 4 + 1] +
              wv.z * hl[k4 * 4 + 2] + wv.w * hl[k4 * 4 + 3];
    }
    s_red[tid] = part;
    __syncthreads();
    if (tid < 32) {
      float sum = 0.f;
#pragma unroll
      for (int kk = 0; kk < 16; ++kk) sum += s_red[kk * 32 + tid];
      int ii = (wg & 3) * 32 + tid;
      coh_store1(out + ((size_t)tt * B + b) * I_DIM + ii, sum + b_out[ii]);
    }
    __syncthreads();
  };

  // ---- inp(tn) = sigmoid(x[tn] @ w_in^T + b_in) -> cols {2wg,2wg+1} ----
  auto inp_block = [&](int tn, int par) {
    const int b = tid & 63, cc = (tid >> 6) & 1, ks = tid >> 7;  // ks 0..3
    const int col = wg * 2 + cc;
    const float* xsrc = x + ((size_t)tn * B + b) * I_DIM + ks * 32;
    const float* wrow = w_in + (size_t)col * I_DIM + ks * 32;
    float part = 0.f;
#pragma unroll
    for (int k4 = 0; k4 < 8; ++k4) {
      float4 xv = *reinterpret_cast<const float4*>(xsrc + k4 * 4);
      float4 wv = *reinterpret_cast<const float4*>(wrow + k4 * 4);
      part += xv.x * wv.x + xv.y * wv.y + xv.z * wv.z + xv.w * wv.w;
    }
    s_red[tid] = part;
    __syncthreads();
    if (tid < 128) {
      float v = s_red[tid] + s_red[tid + 128] + s_red[tid + 256] +
                s_red[tid + 384];
      int col2 = wg * 2 + (tid >> 6), b2 = tid & 63;
      coh_store1(ws + OFF_INP + par * HB + col2 * 64 + b2, sigm(v + b_in[col2]));
    }
    __syncthreads();
  };

  // ---- gates gemv: 8 rows x 64 b, K=1024 = [lo(512);hi(512)], k-major.
  // Weights from persistent LDS; activations via plain cached loads
  // (post-fence fresh; L1/L2 serve the 256-WG broadcast). ----
  auto gemv = [&](const float* __restrict__ lo, const float* __restrict__ hi,
                  const int layer) {
    const int s = tid >> 3;  // k-slice 0..63
    const int tb = tid & 7;  // batch octet
    const int wbase = ((layer * 8) * 64 + s) * P;
    float acc[64];
#pragma unroll
    for (int q = 0; q < 64; ++q) acc[q] = 0.f;

    f32x4 a_cur[4][2], a_nxt[4][2];
#pragma unroll
    for (int c = 0; c < 4; ++c) {
      const float* p = lo + c * 4096 + s * 64 + tb * 8;
      a_cur[c][0] = *reinterpret_cast<const f32x4*>(p);
      a_cur[c][1] = *reinterpret_cast<const f32x4*>(p + 4);
    }
#pragma unroll
    for (int g = 0; g < 4; ++g) {
      if (g < 3) {
#pragma unroll
        for (int cc = 0; cc < 4; ++cc) {
          const int c = (g + 1) * 4 + cc;
          const float* p =
              (c < 8 ? lo + c * 4096 : hi + (c - 8) * 4096) + s * 64 + tb * 8;
          a_nxt[cc][0] = *reinterpret_cast<const f32x4*>(p);
          a_nxt[cc][1] = *reinterpret_cast<const f32x4*>(p + 4);
        }
      }
      float4 wr[8];
#pragma unroll
      for (int r = 0; r < 8; ++r)
        wr[r] = *reinterpret_cast<const float4*>(
            &s_w[wbase + r * (64 * P) + g * 4]);
#pragma unroll
      for (int cc = 0; cc < 4; ++cc) {
        float av[8] = {a_cur[cc][0].x, a_cur[cc][0].y, a_cur[cc][0].z,
                       a_cur[cc][0].w, a_cur[cc][1].x, a_cur[cc][1].y,
                       a_cur[cc][1].z, a_cur[cc][1].w};
#pragma unroll
        for (int r = 0; r < 8; ++r) {
          float w = (cc == 0) ? wr[r].x
                  : (cc == 1) ? wr[r].y
                  : (cc == 2) ? wr[r].z
                              : wr[r].w;
#pragma unroll
          for (int bb = 0; bb < 8; ++bb)
            acc[r * 8 + bb] = fmaf(w, av[bb], acc[r * 8 + bb]);
        }
      }
      if (g < 3) {
#pragma unroll
        for (int cc = 0; cc < 4; ++cc) {
          a_cur[cc][0] = a_nxt[cc][0];
          a_cur[cc][1] = a_nxt[cc][1];
        }
      }
    }

    // ---- exchange-and-halve reduction over lane bits 3..5 ----
    const int lane = tid & 63;
    const bool b3 = (lane & 8) != 0;
    const bool b4 = (lane & 16) != 0;
    const bool b5 = (lane & 32) != 0;
    float v32[32];
#pragma unroll
    for (int go = 0; go < 4; ++go)
#pragma unroll
      for (int j = 0; j < 8; ++j) {
        float lc = acc[(2 * go + 0) * 8 + j];
        float hc = acc[(2 * go + 1) * 8 + j];
        float lo_o = __shfl_xor(lc, 8, 64);
        float hi_o = __shfl_xor(hc, 8, 64);
        v32[go * 8 + j] = b3 ? (hc + hi_o) : (lc + lo_o);
      }
    float v16[16];
#pragma unroll
    for (int go = 0; go < 2; ++go)
#pragma unroll
      for (int j = 0; j < 8; ++j) {
        float lc = v32[(2 * go + 0) * 8 + j];
        float hc = v32[(2 * go + 1) * 8 + j];
        float lo_o = __shfl_xor(lc, 16, 64);
        float hi_o = __shfl_xor(hc, 16, 64);
        v16[go * 8 + j] = b4 ? (hc + hi_o) : (lc + lo_o);
      }
    float fin[8];
#pragma unroll
    for (int j = 0; j < 8; ++j) {
      float lc = v16[j];
      float hc = v16[8 + j];
      float lo_o = __shfl_xor(lc, 32, 64);
      float hi_o = __shfl_xor(hc, 32, 64);
      fin[j] = b5 ? (hc + hi_o) : (lc + lo_o);
    }
    const int wv = tid >> 6;
    const int sigma = (lane >> 3) & 7;
    float* dst = s_red + wv * 512 + sigma * 64 + tb * 8;
    *reinterpret_cast<float4*>(dst) = make_float4(fin[0], fin[1], fin[2], fin[3]);
    *reinterpret_cast<float4*>(dst + 4) =
        make_float4(fin[4], fin[5], fin[6], fin[7]);
    __syncthreads();
    {
      const float* bsum_l = ws + OFF_BSUM + layer * 4 * H;
      float sum = 0.f;
#pragma unroll
      for (int w8 = 0; w8 < 8; ++w8) sum += s_red[w8 * 512 + tid];
      int r = tid >> 6;
      int grow = (r >> 1) * 512 + wg * 2 + (r & 1);
      s_g[tid] = sum + bsum_l[grow];  // s_g[r*64+b]
    }
    __syncthreads();
  };

  float cs0 = 0.f, cs1 = 0.f;  // tid<128 owns (col=2wg+(tid>>6), b=tid&63)

  auto cell0_update = [&](float* dst) {
    if (tid < 128) {
      const int cc = tid >> 6, b = tid & 63, col = wg * 2 + cc;
      float ig = sigm(s_g[(0 + cc) * 64 + b]);
      float fg = sigm(s_g[(2 + cc) * 64 + b]);
      float gt = tanh_fast(s_g[(4 + cc) * 64 + b]);
      float og = sigm(s_g[(6 + cc) * 64 + b]);
      cs0 = fg * cs0 + ig * gt;
      coh_store1(dst + col * 64 + b, og * tanh_fast(cs0));
    }
  };
  auto cell1_update = [&](int p) {
    if (tid < 128) {
      const int cc = tid >> 6, b = tid & 63, col = wg * 2 + cc;
      float ig = sigm(s_g[(0 + cc) * 64 + b]);
      float fg = sigm(s_g[(2 + cc) * 64 + b]);
      float gt = tanh_fast(s_g[(4 + cc) * 64 + b]);
      float og = sigm(s_g[(6 + cc) * 64 + b]);
      cs1 = fg * cs1 + ig * gt;
      coh_store1(ws + OFF_H1 + p * HB + col * 64 + b, og * tanh_fast(cs1));
    }
  };

  // ---------------- prologue ----------------
  inp_block(0, 0);
  inp_block(1, 1);
  gridbar();
  gemv(ws + OFF_INP + 0 * HB, ws + OFF_H0 + 1 * HB, 0);  // h0(-1)=par1 zeros
  cell0_update(ws + OFF_H0 + 0 * HB);
  gridbar();

  // ---------------- main loop: one barrier per step ----------------
  for (int t = 0; t < T_STEPS; ++t) {
    const int p = t & 1;
    gemv(ws + OFF_H0 + p * HB, ws + OFF_H1 + (1 - p) * HB, 1);
    cell1_update(p);
    if (t > 0) out_block(t - 1, 1 - p);
    if (t + 1 < T_STEPS) {
      gemv(ws + OFF_INP + (1 - p) * HB, ws + OFF_H0 + p * HB, 0);
      cell0_update(ws + OFF_H0 + (1 - p) * HB);
    }
    if (t + 2 < T_STEPS) inp_block(t + 2, p);
    gridbar();
  }
  out_block(T_STEPS - 1, 1);
}

extern "C" void kernel_launch(void* const* d_in, const int* in_sizes, int n_in,
                              void* d_out, int out_size, void* d_ws,
                              size_t ws_size, hipStream_t stream) {
  const float* x     = (const float*)d_in[0];
  const float* w_in  = (const float*)d_in[1];
  const float* b_in  = (const float*)d_in[2];
  const float* w_ih  = (const float*)d_in[3];
  const float* w_hh  = (const float*)d_in[4];
  const float* b_ih  = (const float*)d_in[5];
  const float* b_hh  = (const float*)d_in[6];
  const float* w_out = (const float*)d_in[7];
  const float* b_out = (const float*)d_in[8];
  float* ws   = (float*)d_ws;
  float* outp = (float*)d_out;

  hipLaunchKernelGGL(init_ws_kernel, dim3(NBLK), dim3(NTHR), 0, stream, ws,
                     b_ih, b_hh);
  hipLaunchKernelGGL(lstm_kernel, dim3(NBLK), dim3(NTHR), 0, stream, x, w_in,
                     b_in, w_ih, w_hh, w_out, b_out, ws, outp);
}

// Round 3
// 19512.654 us; speedup vs baseline: 1.8128x; 1.8122x over previous
//
#include <hip/hip_runtime.h>
#include <math.h>

// LSTMNN: T=1024, B=64, I=128, H=512, L=2, fp32. Persistent 256 WG x 512 thr.
// Round 7: R6 (layer-pipelined split + L2 broadcast) resubmitted with
// halved code instantiation + faster failsafe after a 2x container failure
// (no counters; R6 logic re-audited clean -> suspect infra/compile bloat).
//   (a) Layer pipeline: wg&1 selects layer. L0 WGs compute h0(tau) while L1
//       WGs compute h1(tau-1). One 16-row gemv per WG per tick (was 2x8):
//       per-WG panel traffic halves, serial gemv phases 2->1, same FLOPs.
//       gemv/cell_update now have a SINGLE call site (pointers picked by
//       layer) to halve compiled size vs R6.
//   (b) Cached activation reads + ONE buffer_inv per WG (wave 0 only),
//       issued BEFORE barrier arrival: arrival => inv complete, so post-
//       release reads are never invalidated mid-stream. Read-set(tau) is
//       disjoint from write-set(tau), so no stale re-fetch window exists.
//   (c) All global data writes remain sc0sc1 write-through: L2 never holds
//       dirty activation lines; MALL always fresh for cross-XCD readers.

namespace {
constexpr int T_STEPS = 1024;
constexpr int B = 64;
constexpr int I_DIM = 128;
constexpr int H = 512;
constexpr int NBLK = 256;
constexpr int NTHR = 512;
constexpr int HB = H * B;  // 32768
constexpr int P = 20;      // padded chunk dim for LDS weights

// ws layout (floats)
constexpr int OFF_INP  = 0;                  // [2][512][64] inp slots
constexpr int OFF_H0   = OFF_INP + 2 * HB;   // [2][512][64] h0 parity
constexpr int OFF_H1   = OFF_H0 + 2 * HB;    // [2][512][64] h1 parity
constexpr int OFF_BSUM = OFF_H1 + 2 * HB;    // [2][2048] b_ih+b_hh
constexpr int OFF_BAR  = OFF_BSUM + 2 * 4 * H;  // barrier state
// barrier slots, stride 64 uints (256B): [0..15] group arrivals,
// [16] master, [17..32] per-group release flags, [33] poison
constexpr int BAR_SLOTS = 34;
constexpr int BAR_UINTS = BAR_SLOTS * 64;  // 2176
}  // namespace

typedef float f32x4 __attribute__((ext_vector_type(4)));

// coherent write-through store (sc0 sc1): lands at the coherence point,
// no dirty L2 line anywhere.
__device__ __forceinline__ void coh_store1(float* p, float v) {
  asm volatile("global_store_dword %0, %1, off sc0 sc1" ::"v"(p), "v"(v)
               : "memory");
}

__global__ __launch_bounds__(NTHR) void init_ws_kernel(
    float* __restrict__ ws, const float* __restrict__ b_ih,
    const float* __restrict__ b_hh) {
  int idx = blockIdx.x * blockDim.x + threadIdx.x;
  for (int f = idx; f < OFF_BSUM; f += NBLK * NTHR) coh_store1(ws + f, 0.f);
  if (idx < 2 * 4 * H) coh_store1(ws + OFF_BSUM + idx, b_ih[idx] + b_hh[idx]);
  if (idx < BAR_UINTS) coh_store1(ws + OFF_BAR + idx, 0.f);  // bits == 0u
}

__device__ __forceinline__ float sigm(float x) {
  return 1.f / (1.f + __expf(-x));
}
__device__ __forceinline__ float tanh_fast(float x) {
  float e = __expf(-2.f * fabsf(x));
  float t = (1.f - e) / (1.f + e);
  return x < 0.f ? -t : t;
}

__global__ __launch_bounds__(NTHR, 2) void lstm_kernel(
    const float* __restrict__ x, const float* __restrict__ w_in,
    const float* __restrict__ b_in, const float* __restrict__ w_ih,
    const float* __restrict__ w_hh, const float* __restrict__ w_out,
    const float* __restrict__ b_out, float* __restrict__ ws,
    float* __restrict__ out) {
  __shared__ float s_w[16 * 64 * P];  // 80 KB persistent gate weights
  __shared__ float s_red[8 * 1024];   // 32 KB reduction scratch
  __shared__ float s_g[1024];         // 4 KB gate pre-activations
  __shared__ float s_h1[512];         // 2 KB gathered h1 column (out)

  const int tid = threadIdx.x;
  const int wg = blockIdx.x;
  const int layer = wg & 1;
  const int lid = wg >> 1;  // 0..127: owns h-columns lid*4 .. +3
  unsigned* const bar = reinterpret_cast<unsigned*>(ws + OFF_BAR);

  // ---- persistent weight load: s_w[(r*64+ss)*P + c] = W[layer][grow][k],
  //      r = q*4+j (q=gate, j=col-within-4), grow = q*512 + lid*4 + j,
  //      k = c*64 + ss (K-concat: k<512 -> w_ih, else w_hh) ----
#pragma unroll
  for (int i = 0; i < 8; ++i) {
    int idx = i * 512 + tid;  // float4 unit 0..4095
    int r = idx >> 8;         // 0..15
    int k0 = (idx & 255) * 4;
    int grow = (r >> 2) * 512 + lid * 4 + (r & 3);
    const float* srcp =
        (k0 < 512) ? (w_ih + ((size_t)layer * 4 * H + grow) * H + k0)
                   : (w_hh + ((size_t)layer * 4 * H + grow) * H + (k0 - 512));
    float4 v = *reinterpret_cast<const float4*>(srcp);
    float arr[4] = {v.x, v.y, v.z, v.w};
#pragma unroll
    for (int j = 0; j < 4; ++j) {
      int k = k0 + j;
      int c = k >> 6, ss = k & 63;
      s_w[(r * 64 + ss) * P + c] = arr[j];
    }
  }
  __syncthreads();

  // ---- pre-barrier L2/L1 invalidate: wave 0 only. Barrier arrival implies
  //      this WG's inv completed (gridbar's syncthreads drains wave0). ----
  auto pre_inv = [&]() {
    if (tid < 64) __builtin_amdgcn_fence(__ATOMIC_ACQUIRE, "agent");
  };

  // ---- grid barrier: padded monotonic 2-level, per-group release flags ----
  unsigned bar_gen = 0;
  auto gridbar = [&]() {
    ++bar_gen;
    __syncthreads();  // drains vmcnt: sc0sc1 stores at coherence point AND
                      // wave0's buffer_inv complete before leader signs in
    if (tid == 0) {
      if (__hip_atomic_load(bar + 33 * 64, __ATOMIC_RELAXED,
                            __HIP_MEMORY_SCOPE_AGENT) == 0u) {
        const unsigned grp = (unsigned)wg & 15u;
        unsigned prev = __hip_atomic_fetch_add(
            bar + grp * 64, 1u, __ATOMIC_RELAXED, __HIP_MEMORY_SCOPE_AGENT);
        bool done = false;
        if ((prev & 15u) == 15u) {  // last of group (monotonic count)
          unsigned mprev = __hip_atomic_fetch_add(
              bar + 16 * 64, 1u, __ATOMIC_RELAXED, __HIP_MEMORY_SCOPE_AGENT);
          if ((mprev & 15u) == 15u) {  // last group: release everyone
#pragma unroll
            for (int g2 = 0; g2 < 16; ++g2)
              __hip_atomic_store(bar + (17 + g2) * 64, bar_gen,
                                 __ATOMIC_RELAXED, __HIP_MEMORY_SCOPE_AGENT);
            done = true;
          }
        }
        if (!done) {
          unsigned spin = 0;
          while (__hip_atomic_load(bar + (17 + grp) * 64, __ATOMIC_RELAXED,
                                   __HIP_MEMORY_SCOPE_AGENT) < bar_gen) {
            __builtin_amdgcn_s_sleep(1);
            if ((++spin & 255u) == 0u) {
              if (__hip_atomic_load(bar + 33 * 64, __ATOMIC_RELAXED,
                                    __HIP_MEMORY_SCOPE_AGENT) != 0u)
                break;
              if (spin > (1u << 19)) {  // failsafe: fast-fail, don't hang
                __hip_atomic_store(bar + 33 * 64, 1u, __ATOMIC_RELAXED,
                                   __HIP_MEMORY_SCOPE_AGENT);
                break;
              }
            }
          }
        }
      }
    }
    __syncthreads();
  };

  // ---- gates gemv: 16 rows x 64 b, K=1024 = [lo(512);hi(512)], k-major.
  //      Weights from LDS; activations via plain cached loads (L2-served
  //      broadcast; fresh because every WG inv'd before barrier arrival). ----
  auto gemv = [&](const float* __restrict__ lo, const float* __restrict__ hi) {
    const int s = tid >> 3;  // k-slice 0..63
    const int tb = tid & 7;  // batch octet
    const int abase = s * 64 + tb * 8;
    float acc[128];
#pragma unroll
    for (int q = 0; q < 128; ++q) acc[q] = 0.f;

    f32x4 a_cur[4][2], a_nxt[4][2];
#pragma unroll
    for (int c = 0; c < 4; ++c) {
      const float* p = lo + c * 4096 + abase;
      a_cur[c][0] = *reinterpret_cast<const f32x4*>(p);
      a_cur[c][1] = *reinterpret_cast<const f32x4*>(p + 4);
    }
#pragma unroll
    for (int g = 0; g < 4; ++g) {
      if (g < 3) {
#pragma unroll
        for (int cc = 0; cc < 4; ++cc) {
          const int c = (g + 1) * 4 + cc;
          const float* p =
              (c < 8 ? lo + c * 4096 : hi + (c - 8) * 4096) + abase;
          a_nxt[cc][0] = *reinterpret_cast<const f32x4*>(p);
          a_nxt[cc][1] = *reinterpret_cast<const f32x4*>(p + 4);
        }
      }
      // rows in two halves of 8 to cap live wr[] registers
#pragma unroll
      for (int rh = 0; rh < 2; ++rh) {
        float4 wr[8];
#pragma unroll
        for (int r8 = 0; r8 < 8; ++r8)
          wr[r8] = *reinterpret_cast<const float4*>(
              &s_w[((rh * 8 + r8) * 64 + s) * P + g * 4]);
#pragma unroll
        for (int cc = 0; cc < 4; ++cc) {
          float av[8] = {a_cur[cc][0].x, a_cur[cc][0].y, a_cur[cc][0].z,
                         a_cur[cc][0].w, a_cur[cc][1].x, a_cur[cc][1].y,
                         a_cur[cc][1].z, a_cur[cc][1].w};
#pragma unroll
          for (int r8 = 0; r8 < 8; ++r8) {
            float w = (cc == 0)   ? wr[r8].x
                      : (cc == 1) ? wr[r8].y
                      : (cc == 2) ? wr[r8].z
                                  : wr[r8].w;
#pragma unroll
            for (int bb = 0; bb < 8; ++bb)
              acc[(rh * 8 + r8) * 8 + bb] =
                  fmaf(w, av[bb], acc[(rh * 8 + r8) * 8 + bb]);
          }
        }
      }
      if (g < 3) {
#pragma unroll
        for (int cc = 0; cc < 4; ++cc) {
          a_cur[cc][0] = a_nxt[cc][0];
          a_cur[cc][1] = a_nxt[cc][1];
        }
      }
    }

    // ---- exchange-and-halve reduction over lane bits 3..5 ----
    const int lane = tid & 63;
    const bool b3 = (lane & 8) != 0;
    const bool b4 = (lane & 16) != 0;
    const bool b5 = (lane & 32) != 0;
    float v1[64];
#pragma unroll
    for (int go = 0; go < 8; ++go)
#pragma unroll
      for (int j = 0; j < 8; ++j) {
        float lc = acc[(2 * go + 0) * 8 + j];
        float hc = acc[(2 * go + 1) * 8 + j];
        float lo_o = __shfl_xor(lc, 8, 64);
        float hi_o = __shfl_xor(hc, 8, 64);
        v1[go * 8 + j] = b3 ? (hc + hi_o) : (lc + lo_o);
      }
    float v2[32];
#pragma unroll
    for (int go = 0; go < 4; ++go)
#pragma unroll
      for (int j = 0; j < 8; ++j) {
        float lc = v1[(2 * go + 0) * 8 + j];
        float hc = v1[(2 * go + 1) * 8 + j];
        float lo_o = __shfl_xor(lc, 16, 64);
        float hi_o = __shfl_xor(hc, 16, 64);
        v2[go * 8 + j] = b4 ? (hc + hi_o) : (lc + lo_o);
      }
    float fin[16];
#pragma unroll
    for (int go = 0; go < 2; ++go)
#pragma unroll
      for (int j = 0; j < 8; ++j) {
        float lc = v2[(2 * go + 0) * 8 + j];
        float hc = v2[(2 * go + 1) * 8 + j];
        float lo_o = __shfl_xor(lc, 32, 64);
        float hi_o = __shfl_xor(hc, 32, 64);
        fin[go * 8 + j] = b5 ? (hc + hi_o) : (lc + lo_o);
      }
    // lane holds rows {sigma, 8+sigma} for b = tb*8 + j
    const int wv = tid >> 6;
    const int sigma = (lane >> 3) & 7;
    float* dst0 = s_red + wv * 1024 + sigma * 64 + tb * 8;
    *reinterpret_cast<float4*>(dst0) =
        make_float4(fin[0], fin[1], fin[2], fin[3]);
    *reinterpret_cast<float4*>(dst0 + 4) =
        make_float4(fin[4], fin[5], fin[6], fin[7]);
    float* dst1 = dst0 + 512;  // rows 8+sigma
    *reinterpret_cast<float4*>(dst1) =
        make_float4(fin[8], fin[9], fin[10], fin[11]);
    *reinterpret_cast<float4*>(dst1 + 4) =
        make_float4(fin[12], fin[13], fin[14], fin[15]);
    __syncthreads();
    {
      const float* bsum_l = ws + OFF_BSUM + layer * 2048;
#pragma unroll
      for (int h2 = 0; h2 < 2; ++h2) {
        int o = h2 * 512 + tid;
        float sum = 0.f;
#pragma unroll
        for (int w8 = 0; w8 < 8; ++w8) sum += s_red[w8 * 1024 + o];
        int r = o >> 6;
        int grow = (r >> 2) * 512 + lid * 4 + (r & 3);
        s_g[o] = sum + bsum_l[grow];  // s_g[r*64 + b]
      }
    }
    __syncthreads();
  };

  float cs = 0.f;  // tid<256 owns cell state (col = lid*4 + (tid>>6), b)

  auto cell_update = [&](float* dst) {
    if (tid < 256) {
      const int j = tid >> 6, b = tid & 63, col = lid * 4 + j;
      float ig = sigm(s_g[j * 64 + b]);
      float fg = sigm(s_g[(4 + j) * 64 + b]);
      float gt = tanh_fast(s_g[(8 + j) * 64 + b]);
      float og = sigm(s_g[(12 + j) * 64 + b]);
      cs = fg * cs + ig * gt;
      coh_store1(dst + col * 64 + b, og * tanh_fast(cs));
    }
  };

  // ---- inp(tn) = sigmoid(x[tn] @ w_in^T + b_in) -> cols lid*4..+3 ----
  auto inp_block = [&](int tn, int slot) {
    const int b = tid & 63, jj = (tid >> 6) & 3, kh = tid >> 8;
    const int col = lid * 4 + jj;
    const float* xsrc = x + ((size_t)tn * B + b) * I_DIM + kh * 64;
    const float* wrow = w_in + (size_t)col * I_DIM + kh * 64;
    float part = 0.f;
#pragma unroll
    for (int k4 = 0; k4 < 16; ++k4) {
      float4 xv = *reinterpret_cast<const float4*>(xsrc + k4 * 4);
      float4 wv = *reinterpret_cast<const float4*>(wrow + k4 * 4);
      part += xv.x * wv.x + xv.y * wv.y + xv.z * wv.z + xv.w * wv.w;
    }
    s_red[tid] = part;
    __syncthreads();
    if (tid < 256) {
      float v = s_red[tid] + s_red[tid + 256];
      const int jj2 = (tid >> 6) & 3, b2 = tid & 63;
      const int col2 = lid * 4 + jj2;
      coh_store1(ws + OFF_INP + (size_t)slot * HB + col2 * 64 + b2,
                 sigm(v + b_in[col2]));
    }
    __syncthreads();
  };

  // ---- out(tt): gather h1 column b into LDS once, then reduce ----
  auto out_block = [&](int tt, int par) {
    const int b = lid >> 1, ihalf = lid & 1;
    s_h1[tid] = ws[OFF_H1 + (size_t)par * HB + tid * 64 + b];  // cached
    __syncthreads();
    const int io = tid & 63, ks = tid >> 6;  // ks 0..7, 64 k each
    const int i = ihalf * 64 + io;
    const float* wrow = w_out + (size_t)i * H + ks * 64;
    const float* hl = s_h1 + ks * 64;  // broadcast across io lanes
    float part = 0.f;
#pragma unroll
    for (int k4 = 0; k4 < 16; ++k4) {
      float4 wv = *reinterpret_cast<const float4*>(wrow + k4 * 4);
      part += wv.x * hl[k4 * 4 + 0] + wv.y * hl[k4 * 4 + 1] +
              wv.z * hl[k4 * 4 + 2] + wv.w * hl[k4 * 4 + 3];
    }
    s_red[tid] = part;
    __syncthreads();
    if (tid < 64) {
      float sum = 0.f;
#pragma unroll
      for (int kk = 0; kk < 8; ++kk) sum += s_red[kk * 64 + tid];
      const int ii = ihalf * 64 + tid;
      coh_store1(out + ((size_t)tt * B + b) * I_DIM + ii, sum + b_out[ii]);
    }
    __syncthreads();
  };

  // ---------------- prologue ----------------
  if (layer == 0) inp_block(0, 0);
  pre_inv();
  gridbar();

  // ---------------- pipelined main loop: one barrier per tick ----------
  // tick tau: L0 computes h0(tau) and inp(tau+1); L1 computes h1(tau-1)
  // and out(tau-2). SINGLE gemv/cell call site (pointers by layer).
  for (int tau = 0; tau <= T_STEPS + 1; ++tau) {
    const int pt = tau & 1;
    const float* glo;
    const float* ghi;
    float* gdst;
    bool do_gemv;
    if (layer == 0) {
      glo = ws + OFF_INP + (size_t)pt * HB;
      ghi = ws + OFF_H0 + (size_t)(1 - pt) * HB;
      gdst = ws + OFF_H0 + (size_t)pt * HB;
      do_gemv = (tau < T_STEPS);
    } else {
      glo = ws + OFF_H0 + (size_t)(1 - pt) * HB;
      ghi = ws + OFF_H1 + (size_t)pt * HB;
      gdst = ws + OFF_H1 + (size_t)(1 - pt) * HB;
      do_gemv = (tau >= 1 && tau <= T_STEPS);
    }
    if (do_gemv) {
      gemv(glo, ghi);
      cell_update(gdst);
    }
    if (layer == 0) {
      if (tau + 1 < T_STEPS) inp_block(tau + 1, 1 - pt);
    } else {
      if (tau >= 2) out_block(tau - 2, pt);
    }
    if (tau <= T_STEPS) {  // no barrier after final out-only tick
      pre_inv();
      gridbar();
    }
  }
}

extern "C" void kernel_launch(void* const* d_in, const int* in_sizes, int n_in,
                              void* d_out, int out_size, void* d_ws,
                              size_t ws_size, hipStream_t stream) {
  const float* x     = (const float*)d_in[0];
  const float* w_in  = (const float*)d_in[1];
  const float* b_in  = (const float*)d_in[2];
  const float* w_ih  = (const float*)d_in[3];
  const float* w_hh  = (const float*)d_in[4];
  const float* b_ih  = (const float*)d_in[5];
  const float* b_hh  = (const float*)d_in[6];
  const float* w_out = (const float*)d_in[7];
  const float* b_out = (const float*)d_in[8];
  float* ws   = (float*)d_ws;
  float* outp = (float*)d_out;

  hipLaunchKernelGGL(init_ws_kernel, dim3(NBLK), dim3(NTHR), 0, stream, ws,
                     b_ih, b_hh);
  hipLaunchKernelGGL(lstm_kernel, dim3(NBLK), dim3(NTHR), 0, stream, x, w_in,
                     b_in, w_ih, w_hh, w_out, b_out, ws, outp);
}

// Round 4
// 18737.019 us; speedup vs baseline: 1.8879x; 1.0414x over previous
//
#include <hip/hip_runtime.h>
#include <math.h>

// LSTMNN: T=1024, B=64, I=128, H=512, L=2, fp32. Persistent 256 WG x 512 thr.
// Round 8: make the L2 broadcast real via address rotation.
//   R7 post-mortem: per-tick per-WG agent fences (32 invs/XCD/tick, staggered
//   through the read phase) kept killing co-resident WGs' unread panel lines
//   -> all 64MB/tick of activation reads came from MALL. R7 = "R4 at half
//   volume" (34.5us -> 19us), not "R4 with L2 caching".
//   (a) 8-deep slot rotation for inp/h0/h1 (slot = timestep & 7): a slot's
//       address is re-read (new data) only 8 ticks after its last read, so
//       stale L2 lines are harmless for 7 ticks.
//   (b) Agent-acquire fence (L1+L2 inv) only every 7th barrier (k%7==0),
//       pre-arrival. Window proof: data written tick w is read w+1..w+2 and
//       its slot rewritten at w+8; any stale copy is killed by an inv at
//       some barrier in a 7-barrier window that P=7 always hits. 6/7 of
//       ticks run with ZERO L2 invalidation -> panel reads are L2 hits.
//   (c) Per-tick per-wave `buffer_inv sc0` (vector-L1 flash inv, local,
//       no traffic) after each release: L1 can never serve cross-tick
//       stale lines. This was the only thing the per-tick agent fence was
//       truly needed for.
//   (d) Arrive/wait split: out_block (tick-start-fresh h1) and inp_block
//       (RO x, written 2 ticks ahead) run between barrier arrival and
//       release-wait -> hidden under barrier latency + skew. Their stores
//       drain at the NEXT arrival's syncthreads, one barrier before any
//       consumer reads them.
//   All global data stores remain sc0sc1 write-through: MALL is always
//   fresh; L2s never hold dirty activation lines.

namespace {
constexpr int T_STEPS = 1024;
constexpr int B = 64;
constexpr int I_DIM = 128;
constexpr int H = 512;
constexpr int NBLK = 256;
constexpr int NTHR = 512;
constexpr int HB = H * B;   // 32768 floats = 128 KB
constexpr int NSLOT = 8;    // rotation depth
constexpr int P = 20;       // padded chunk dim for LDS weights

// ws layout (floats): 3 rotated streams + biases + barrier
constexpr int OFF_INP  = 0;                      // [8][512][64]
constexpr int OFF_H0   = OFF_INP + NSLOT * HB;   // [8][512][64]
constexpr int OFF_H1   = OFF_H0 + NSLOT * HB;    // [8][512][64]
constexpr int OFF_BSUM = OFF_H1 + NSLOT * HB;    // [2][2048] b_ih+b_hh
constexpr int OFF_BAR  = OFF_BSUM + 2 * 4 * H;   // barrier state
// barrier slots, stride 64 uints (256B): [0..15] group arrivals,
// [16] master, [17..32] per-group release flags, [33] poison
constexpr int BAR_SLOTS = 34;
constexpr int BAR_UINTS = BAR_SLOTS * 64;  // 2176
}  // namespace

typedef float f32x4 __attribute__((ext_vector_type(4)));

// coherent write-through store (sc0 sc1): lands at the coherence point,
// no dirty L2 line anywhere.
__device__ __forceinline__ void coh_store1(float* p, float v) {
  asm volatile("global_store_dword %0, %1, off sc0 sc1" ::"v"(p), "v"(v)
               : "memory");
}

__global__ __launch_bounds__(NTHR) void init_ws_kernel(
    float* __restrict__ ws, const float* __restrict__ b_ih,
    const float* __restrict__ b_hh) {
  int idx = blockIdx.x * blockDim.x + threadIdx.x;
  for (int f = idx; f < OFF_BSUM; f += NBLK * NTHR) coh_store1(ws + f, 0.f);
  if (idx < 2 * 4 * H) coh_store1(ws + OFF_BSUM + idx, b_ih[idx] + b_hh[idx]);
  if (idx < BAR_UINTS) coh_store1(ws + OFF_BAR + idx, 0.f);  // bits == 0u
}

__device__ __forceinline__ float sigm(float x) {
  return 1.f / (1.f + __expf(-x));
}
__device__ __forceinline__ float tanh_fast(float x) {
  float e = __expf(-2.f * fabsf(x));
  float t = (1.f - e) / (1.f + e);
  return x < 0.f ? -t : t;
}

__global__ __launch_bounds__(NTHR, 2) void lstm_kernel(
    const float* __restrict__ x, const float* __restrict__ w_in,
    const float* __restrict__ b_in, const float* __restrict__ w_ih,
    const float* __restrict__ w_hh, const float* __restrict__ w_out,
    const float* __restrict__ b_out, float* __restrict__ ws,
    float* __restrict__ out) {
  __shared__ float s_w[16 * 64 * P];  // 80 KB persistent gate weights
  __shared__ float s_red[8 * 1024];   // 32 KB reduction scratch
  __shared__ float s_g[1024];         // 4 KB gate pre-activations
  __shared__ float s_h1[512];         // 2 KB gathered h1 column (out)

  const int tid = threadIdx.x;
  const int wg = blockIdx.x;
  const int layer = wg & 1;
  const int lid = wg >> 1;  // 0..127: owns h-columns lid*4 .. +3
  unsigned* const bar = reinterpret_cast<unsigned*>(ws + OFF_BAR);

  // ---- persistent weight load: s_w[(r*64+ss)*P + c] = W[layer][grow][k],
  //      r = q*4+j (q=gate, j=col-within-4), grow = q*512 + lid*4 + j,
  //      k = c*64 + ss (K-concat: k<512 -> w_ih, else w_hh) ----
#pragma unroll
  for (int i = 0; i < 8; ++i) {
    int idx = i * 512 + tid;  // float4 unit 0..4095
    int r = idx >> 8;         // 0..15
    int k0 = (idx & 255) * 4;
    int grow = (r >> 2) * 512 + lid * 4 + (r & 3);
    const float* srcp =
        (k0 < 512) ? (w_ih + ((size_t)layer * 4 * H + grow) * H + k0)
                   : (w_hh + ((size_t)layer * 4 * H + grow) * H + (k0 - 512));
    float4 v = *reinterpret_cast<const float4*>(srcp);
    float arr[4] = {v.x, v.y, v.z, v.w};
#pragma unroll
    for (int j = 0; j < 4; ++j) {
      int k = k0 + j;
      int c = k >> 6, ss = k & 63;
      s_w[(r * 64 + ss) * P + c] = arr[j];
    }
  }
  __syncthreads();

  // ---- split grid barrier: arrive (with optional pre-arrival L2 inv),
  //      then window work, then wait + per-wave L1 inv ----
  unsigned bar_gen = 0;
  auto bar_arrive = [&](bool inv_l2) {
    ++bar_gen;
    if (inv_l2 && tid < 64) {
      // agent acquire: s_waitcnt + buffer_inv (L1+L2). Completes before
      // this WG's arrival (syncthreads below drains wave0's vmcnt).
      __builtin_amdgcn_fence(__ATOMIC_ACQUIRE, "agent");
    }
    __syncthreads();  // drains vmcnt per wave: all sc0sc1 data stores are
                      // at the coherence point before the leader signs in
    if (tid == 0) {
      if (__hip_atomic_load(bar + 33 * 64, __ATOMIC_RELAXED,
                            __HIP_MEMORY_SCOPE_AGENT) == 0u) {
        const unsigned grp = (unsigned)wg & 15u;
        unsigned prev = __hip_atomic_fetch_add(
            bar + grp * 64, 1u, __ATOMIC_RELAXED, __HIP_MEMORY_SCOPE_AGENT);
        if ((prev & 15u) == 15u) {  // last of group (monotonic count)
          unsigned mprev = __hip_atomic_fetch_add(
              bar + 16 * 64, 1u, __ATOMIC_RELAXED, __HIP_MEMORY_SCOPE_AGENT);
          if ((mprev & 15u) == 15u) {  // last group: release everyone
#pragma unroll
            for (int g2 = 0; g2 < 16; ++g2)
              __hip_atomic_store(bar + (17 + g2) * 64, bar_gen,
                                 __ATOMIC_RELAXED, __HIP_MEMORY_SCOPE_AGENT);
          }
        }
      }
    }
  };
  auto bar_wait = [&]() {
    if (tid == 0) {
      if (__hip_atomic_load(bar + 33 * 64, __ATOMIC_RELAXED,
                            __HIP_MEMORY_SCOPE_AGENT) == 0u) {
        const unsigned grp = (unsigned)wg & 15u;
        unsigned spin = 0;
        while (__hip_atomic_load(bar + (17 + grp) * 64, __ATOMIC_RELAXED,
                                 __HIP_MEMORY_SCOPE_AGENT) < bar_gen) {
          __builtin_amdgcn_s_sleep(1);
          if ((++spin & 255u) == 0u) {
            if (__hip_atomic_load(bar + 33 * 64, __ATOMIC_RELAXED,
                                  __HIP_MEMORY_SCOPE_AGENT) != 0u)
              break;
            if (spin > (1u << 19)) {  // failsafe: fast-fail, don't hang
              __hip_atomic_store(bar + 33 * 64, 1u, __ATOMIC_RELAXED,
                                 __HIP_MEMORY_SCOPE_AGENT);
              break;
            }
          }
        }
      }
    }
    __syncthreads();
    // per-wave vector-L1 flash invalidate (local CU only, no L2 effect):
    // no cross-tick stale line can be served from L1. Wait for the inv
    // (vmcnt-tracked) before any subsequent load can issue.
    asm volatile("buffer_inv sc0" ::: "memory");
    asm volatile("s_waitcnt vmcnt(0)" ::: "memory");
  };

  // ---- gates gemv: 16 rows x 64 b, K=1024 = [lo(512);hi(512)], k-major.
  //      Weights from LDS; activations via plain cached loads (true L2
  //      broadcast: no mid-read invalidation on 6/7 of ticks). ----
  auto gemv = [&](const float* __restrict__ lo, const float* __restrict__ hi) {
    const int s = tid >> 3;  // k-slice 0..63
    const int tb = tid & 7;  // batch octet
    const int abase = s * 64 + tb * 8;
    float acc[128];
#pragma unroll
    for (int q = 0; q < 128; ++q) acc[q] = 0.f;

    f32x4 a_cur[4][2], a_nxt[4][2];
#pragma unroll
    for (int c = 0; c < 4; ++c) {
      const float* p = lo + c * 4096 + abase;
      a_cur[c][0] = *reinterpret_cast<const f32x4*>(p);
      a_cur[c][1] = *reinterpret_cast<const f32x4*>(p + 4);
    }
#pragma unroll
    for (int g = 0; g < 4; ++g) {
      if (g < 3) {
#pragma unroll
        for (int cc = 0; cc < 4; ++cc) {
          const int c = (g + 1) * 4 + cc;
          const float* p =
              (c < 8 ? lo + c * 4096 : hi + (c - 8) * 4096) + abase;
          a_nxt[cc][0] = *reinterpret_cast<const f32x4*>(p);
          a_nxt[cc][1] = *reinterpret_cast<const f32x4*>(p + 4);
        }
      }
      // rows in two halves of 8 to cap live wr[] registers
#pragma unroll
      for (int rh = 0; rh < 2; ++rh) {
        float4 wr[8];
#pragma unroll
        for (int r8 = 0; r8 < 8; ++r8)
          wr[r8] = *reinterpret_cast<const float4*>(
              &s_w[((rh * 8 + r8) * 64 + s) * P + g * 4]);
#pragma unroll
        for (int cc = 0; cc < 4; ++cc) {
          float av[8] = {a_cur[cc][0].x, a_cur[cc][0].y, a_cur[cc][0].z,
                         a_cur[cc][0].w, a_cur[cc][1].x, a_cur[cc][1].y,
                         a_cur[cc][1].z, a_cur[cc][1].w};
#pragma unroll
          for (int r8 = 0; r8 < 8; ++r8) {
            float w = (cc == 0)   ? wr[r8].x
                      : (cc == 1) ? wr[r8].y
                      : (cc == 2) ? wr[r8].z
                                  : wr[r8].w;
#pragma unroll
            for (int bb = 0; bb < 8; ++bb)
              acc[(rh * 8 + r8) * 8 + bb] =
                  fmaf(w, av[bb], acc[(rh * 8 + r8) * 8 + bb]);
          }
        }
      }
      if (g < 3) {
#pragma unroll
        for (int cc = 0; cc < 4; ++cc) {
          a_cur[cc][0] = a_nxt[cc][0];
          a_cur[cc][1] = a_nxt[cc][1];
        }
      }
    }

    // ---- exchange-and-halve reduction over lane bits 3..5 ----
    const int lane = tid & 63;
    const bool b3 = (lane & 8) != 0;
    const bool b4 = (lane & 16) != 0;
    const bool b5 = (lane & 32) != 0;
    float v1[64];
#pragma unroll
    for (int go = 0; go < 8; ++go)
#pragma unroll
      for (int j = 0; j < 8; ++j) {
        float lc = acc[(2 * go + 0) * 8 + j];
        float hc = acc[(2 * go + 1) * 8 + j];
        float lo_o = __shfl_xor(lc, 8, 64);
        float hi_o = __shfl_xor(hc, 8, 64);
        v1[go * 8 + j] = b3 ? (hc + hi_o) : (lc + lo_o);
      }
    float v2[32];
#pragma unroll
    for (int go = 0; go < 4; ++go)
#pragma unroll
      for (int j = 0; j < 8; ++j) {
        float lc = v1[(2 * go + 0) * 8 + j];
        float hc = v1[(2 * go + 1) * 8 + j];
        float lo_o = __shfl_xor(lc, 16, 64);
        float hi_o = __shfl_xor(hc, 16, 64);
        v2[go * 8 + j] = b4 ? (hc + hi_o) : (lc + lo_o);
      }
    float fin[16];
#pragma unroll
    for (int go = 0; go < 2; ++go)
#pragma unroll
      for (int j = 0; j < 8; ++j) {
        float lc = v2[(2 * go + 0) * 8 + j];
        float hc = v2[(2 * go + 1) * 8 + j];
        float lo_o = __shfl_xor(lc, 32, 64);
        float hi_o = __shfl_xor(hc, 32, 64);
        fin[go * 8 + j] = b5 ? (hc + hi_o) : (lc + lo_o);
      }
    // lane holds rows {sigma, 8+sigma} for b = tb*8 + j
    const int wv = tid >> 6;
    const int sigma = (lane >> 3) & 7;
    float* dst0 = s_red + wv * 1024 + sigma * 64 + tb * 8;
    *reinterpret_cast<float4*>(dst0) =
        make_float4(fin[0], fin[1], fin[2], fin[3]);
    *reinterpret_cast<float4*>(dst0 + 4) =
        make_float4(fin[4], fin[5], fin[6], fin[7]);
    float* dst1 = dst0 + 512;  // rows 8+sigma
    *reinterpret_cast<float4*>(dst1) =
        make_float4(fin[8], fin[9], fin[10], fin[11]);
    *reinterpret_cast<float4*>(dst1 + 4) =
        make_float4(fin[12], fin[13], fin[14], fin[15]);
    __syncthreads();
    {
      const float* bsum_l = ws + OFF_BSUM + layer * 2048;
#pragma unroll
      for (int h2 = 0; h2 < 2; ++h2) {
        int o = h2 * 512 + tid;
        float sum = 0.f;
#pragma unroll
        for (int w8 = 0; w8 < 8; ++w8) sum += s_red[w8 * 1024 + o];
        int r = o >> 6;
        int grow = (r >> 2) * 512 + lid * 4 + (r & 3);
        s_g[o] = sum + bsum_l[grow];  // s_g[r*64 + b]
      }
    }
    __syncthreads();
  };

  float cs = 0.f;  // tid<256 owns cell state (col = lid*4 + (tid>>6), b)

  auto cell_update = [&](float* dst) {
    if (tid < 256) {
      const int j = tid >> 6, b = tid & 63, col = lid * 4 + j;
      float ig = sigm(s_g[j * 64 + b]);
      float fg = sigm(s_g[(4 + j) * 64 + b]);
      float gt = tanh_fast(s_g[(8 + j) * 64 + b]);
      float og = sigm(s_g[(12 + j) * 64 + b]);
      cs = fg * cs + ig * gt;
      coh_store1(dst + col * 64 + b, og * tanh_fast(cs));
    }
  };

  // ---- inp(tn) = sigmoid(x[tn] @ w_in^T + b_in) -> cols lid*4..+3 ----
  auto inp_block = [&](int tn, int slot) {
    const int b = tid & 63, jj = (tid >> 6) & 3, kh = tid >> 8;
    const int col = lid * 4 + jj;
    const float* xsrc = x + ((size_t)tn * B + b) * I_DIM + kh * 64;
    const float* wrow = w_in + (size_t)col * I_DIM + kh * 64;
    float part = 0.f;
#pragma unroll
    for (int k4 = 0; k4 < 16; ++k4) {
      float4 xv = *reinterpret_cast<const float4*>(xsrc + k4 * 4);
      float4 wv = *reinterpret_cast<const float4*>(wrow + k4 * 4);
      part += xv.x * wv.x + xv.y * wv.y + xv.z * wv.z + xv.w * wv.w;
    }
    s_red[tid] = part;
    __syncthreads();
    if (tid < 256) {
      float v = s_red[tid] + s_red[tid + 256];
      const int jj2 = (tid >> 6) & 3, b2 = tid & 63;
      const int col2 = lid * 4 + jj2;
      coh_store1(ws + OFF_INP + (size_t)slot * HB + col2 * 64 + b2,
                 sigm(v + b_in[col2]));
    }
    __syncthreads();
  };

  // ---- out(tt): gather h1 column b into LDS once, then reduce ----
  auto out_block = [&](int tt, int slot) {
    const int b = lid >> 1, ihalf = lid & 1;
    s_h1[tid] = ws[OFF_H1 + (size_t)slot * HB + tid * 64 + b];  // cached
    __syncthreads();
    const int io = tid & 63, ks = tid >> 6;  // ks 0..7, 64 k each
    const int i = ihalf * 64 + io;
    const float* wrow = w_out + (size_t)i * H + ks * 64;
    const float* hl = s_h1 + ks * 64;  // broadcast across io lanes
    float part = 0.f;
#pragma unroll
    for (int k4 = 0; k4 < 16; ++k4) {
      float4 wv = *reinterpret_cast<const float4*>(wrow + k4 * 4);
      part += wv.x * hl[k4 * 4 + 0] + wv.y * hl[k4 * 4 + 1] +
              wv.z * hl[k4 * 4 + 2] + wv.w * hl[k4 * 4 + 3];
    }
    s_red[tid] = part;
    __syncthreads();
    if (tid < 64) {
      float sum = 0.f;
#pragma unroll
      for (int kk = 0; kk < 8; ++kk) sum += s_red[kk * 64 + tid];
      const int ii = ihalf * 64 + tid;
      coh_store1(out + ((size_t)tt * B + b) * I_DIM + ii, sum + b_out[ii]);
    }
    __syncthreads();
  };

  // ---------------- prologue: inp(0), inp(1); barrier B0 (inv) ----------
  if (layer == 0) {
    inp_block(0, 0);
    inp_block(1, 1);
  }
  bar_arrive(true);  // B0: k=0 -> inv barrier
  bar_wait();

  // ---------------- pipelined main loop: one barrier per tick -----------
  // tick tau: L0 computes h0(tau); L1 computes h1(tau-1). Window work
  // (between arrive and wait): L0 writes inp(tau+2), L1 writes out(tau-2).
  // Barrier after tick tau is B_{tau+1}; inv when (tau+1)%7==0.
  for (int tau = 0; tau <= T_STEPS + 1; ++tau) {
    const int sl = tau & 7;
    const float* glo;
    const float* ghi;
    float* gdst;
    bool do_g;
    if (layer == 0) {
      glo = ws + OFF_INP + (size_t)sl * HB;                  // inp(tau)
      ghi = ws + OFF_H0 + (size_t)((tau - 1) & 7) * HB;      // h0(tau-1)
      gdst = ws + OFF_H0 + (size_t)sl * HB;                  // h0(tau)
      do_g = (tau < T_STEPS);
    } else {
      glo = ws + OFF_H0 + (size_t)((tau - 1) & 7) * HB;      // h0(tau-1)
      ghi = ws + OFF_H1 + (size_t)((tau - 2) & 7) * HB;      // h1(tau-2)
      gdst = ws + OFF_H1 + (size_t)((tau - 1) & 7) * HB;     // h1(tau-1)
      do_g = (tau >= 1 && tau <= T_STEPS);
    }
    if (do_g) {
      gemv(glo, ghi);
      cell_update(gdst);
    }
    if (tau <= T_STEPS) {
      bar_arrive(((tau + 1) % 7) == 0);
      // ---- window work (post-arrival, pre-release) ----
      if (layer == 0) {
        if (tau + 2 <= T_STEPS - 1) inp_block(tau + 2, (tau + 2) & 7);
      } else {
        if (tau >= 2) out_block(tau - 2, (tau - 2) & 7);
      }
      bar_wait();
    } else {
      // final tick (tau == T_STEPS+1): no barrier; L1 emits last output
      if (layer == 1) out_block(tau - 2, (tau - 2) & 7);
    }
  }
}

extern "C" void kernel_launch(void* const* d_in, const int* in_sizes, int n_in,
                              void* d_out, int out_size, void* d_ws,
                              size_t ws_size, hipStream_t stream) {
  const float* x     = (const float*)d_in[0];
  const float* w_in  = (const float*)d_in[1];
  const float* b_in  = (const float*)d_in[2];
  const float* w_ih  = (const float*)d_in[3];
  const float* w_hh  = (const float*)d_in[4];
  const float* b_ih  = (const float*)d_in[5];
  const float* b_hh  = (const float*)d_in[6];
  const float* w_out = (const float*)d_in[7];
  const float* b_out = (const float*)d_in[8];
  float* ws   = (float*)d_ws;
  float* outp = (float*)d_out;

  hipLaunchKernelGGL(init_ws_kernel, dim3(NBLK), dim3(NTHR), 0, stream, ws,
                     b_ih, b_hh);
  hipLaunchKernelGGL(lstm_kernel, dim3(NBLK), dim3(NTHR), 0, stream, x, w_in,
                     b_in, w_ih, w_hh, w_out, b_out, ws, outp);
}

// Round 5
// 17260.013 us; speedup vs baseline: 2.0494x; 1.0856x over previous
//
#include <hip/hip_runtime.h>
#include <math.h>

// LSTMNN: T=1024, B=64, I=128, H=512, L=2, fp32. Persistent 256 WG x 512 thr.
// Round 9: single change vs R8 -> DELETE the per-tick `buffer_inv sc0` +
// vmcnt(0) from bar_wait.
//   R8 post-mortem: removing 6/7 of agent fences gained only 4% -> the
//   per-tick all-wave `buffer_inv sc0` that R8 KEPT is the suspected cache
//   killer (either it invalidates beyond vL1 on gfx950, or 8 redundant
//   flash-invs + vmcnt(0) serialization per CU per tick). It is provably
//   redundant: every stream has reuse distance 8 ticks (inp: write t-2 /
//   read t; h0: write tau / read tau+1; h1: write tau / read tau+1..tau+2;
//   slot rewritten +8), and the 7-periodic agent-acquire fence invalidates
//   BOTH L1 and L2 inside every 8-barrier danger window. So per-tick L1
//   maintenance protects nothing.
//   Kept from R8: 8-deep slot rotation, 7-periodic pre-arrival agent fence,
//   arrive/wait split with window work, sc0sc1 write-through data stores,
//   monotonic padded 2-level barrier.

namespace {
constexpr int T_STEPS = 1024;
constexpr int B = 64;
constexpr int I_DIM = 128;
constexpr int H = 512;
constexpr int NBLK = 256;
constexpr int NTHR = 512;
constexpr int HB = H * B;   // 32768 floats = 128 KB
constexpr int NSLOT = 8;    // rotation depth
constexpr int P = 20;       // padded chunk dim for LDS weights

// ws layout (floats): 3 rotated streams + biases + barrier
constexpr int OFF_INP  = 0;                      // [8][512][64]
constexpr int OFF_H0   = OFF_INP + NSLOT * HB;   // [8][512][64]
constexpr int OFF_H1   = OFF_H0 + NSLOT * HB;    // [8][512][64]
constexpr int OFF_BSUM = OFF_H1 + NSLOT * HB;    // [2][2048] b_ih+b_hh
constexpr int OFF_BAR  = OFF_BSUM + 2 * 4 * H;   // barrier state
// barrier slots, stride 64 uints (256B): [0..15] group arrivals,
// [16] master, [17..32] per-group release flags, [33] poison
constexpr int BAR_SLOTS = 34;
constexpr int BAR_UINTS = BAR_SLOTS * 64;  // 2176
}  // namespace

typedef float f32x4 __attribute__((ext_vector_type(4)));

// coherent write-through store (sc0 sc1): lands at the coherence point,
// no dirty L2 line anywhere.
__device__ __forceinline__ void coh_store1(float* p, float v) {
  asm volatile("global_store_dword %0, %1, off sc0 sc1" ::"v"(p), "v"(v)
               : "memory");
}

__global__ __launch_bounds__(NTHR) void init_ws_kernel(
    float* __restrict__ ws, const float* __restrict__ b_ih,
    const float* __restrict__ b_hh) {
  int idx = blockIdx.x * blockDim.x + threadIdx.x;
  for (int f = idx; f < OFF_BSUM; f += NBLK * NTHR) coh_store1(ws + f, 0.f);
  if (idx < 2 * 4 * H) coh_store1(ws + OFF_BSUM + idx, b_ih[idx] + b_hh[idx]);
  if (idx < BAR_UINTS) coh_store1(ws + OFF_BAR + idx, 0.f);  // bits == 0u
}

__device__ __forceinline__ float sigm(float x) {
  return 1.f / (1.f + __expf(-x));
}
__device__ __forceinline__ float tanh_fast(float x) {
  float e = __expf(-2.f * fabsf(x));
  float t = (1.f - e) / (1.f + e);
  return x < 0.f ? -t : t;
}

__global__ __launch_bounds__(NTHR, 2) void lstm_kernel(
    const float* __restrict__ x, const float* __restrict__ w_in,
    const float* __restrict__ b_in, const float* __restrict__ w_ih,
    const float* __restrict__ w_hh, const float* __restrict__ w_out,
    const float* __restrict__ b_out, float* __restrict__ ws,
    float* __restrict__ out) {
  __shared__ float s_w[16 * 64 * P];  // 80 KB persistent gate weights
  __shared__ float s_red[8 * 1024];   // 32 KB reduction scratch
  __shared__ float s_g[1024];         // 4 KB gate pre-activations
  __shared__ float s_h1[512];         // 2 KB gathered h1 column (out)

  const int tid = threadIdx.x;
  const int wg = blockIdx.x;
  const int layer = wg & 1;
  const int lid = wg >> 1;  // 0..127: owns h-columns lid*4 .. +3
  unsigned* const bar = reinterpret_cast<unsigned*>(ws + OFF_BAR);

  // ---- persistent weight load: s_w[(r*64+ss)*P + c] = W[layer][grow][k],
  //      r = q*4+j (q=gate, j=col-within-4), grow = q*512 + lid*4 + j,
  //      k = c*64 + ss (K-concat: k<512 -> w_ih, else w_hh) ----
#pragma unroll
  for (int i = 0; i < 8; ++i) {
    int idx = i * 512 + tid;  // float4 unit 0..4095
    int r = idx >> 8;         // 0..15
    int k0 = (idx & 255) * 4;
    int grow = (r >> 2) * 512 + lid * 4 + (r & 3);
    const float* srcp =
        (k0 < 512) ? (w_ih + ((size_t)layer * 4 * H + grow) * H + k0)
                   : (w_hh + ((size_t)layer * 4 * H + grow) * H + (k0 - 512));
    float4 v = *reinterpret_cast<const float4*>(srcp);
    float arr[4] = {v.x, v.y, v.z, v.w};
#pragma unroll
    for (int j = 0; j < 4; ++j) {
      int k = k0 + j;
      int c = k >> 6, ss = k & 63;
      s_w[(r * 64 + ss) * P + c] = arr[j];
    }
  }
  __syncthreads();

  // ---- split grid barrier: arrive (with optional pre-arrival L1+L2 inv),
  //      then window work, then wait ----
  unsigned bar_gen = 0;
  auto bar_arrive = [&](bool inv_l2) {
    ++bar_gen;
    if (inv_l2 && tid < 64) {
      // agent acquire: s_waitcnt + buffer_inv (L1+L2). Completes before
      // this WG's arrival (syncthreads below drains wave0's vmcnt).
      __builtin_amdgcn_fence(__ATOMIC_ACQUIRE, "agent");
    }
    __syncthreads();  // drains vmcnt per wave: all sc0sc1 data stores are
                      // at the coherence point before the leader signs in
    if (tid == 0) {
      if (__hip_atomic_load(bar + 33 * 64, __ATOMIC_RELAXED,
                            __HIP_MEMORY_SCOPE_AGENT) == 0u) {
        const unsigned grp = (unsigned)wg & 15u;
        unsigned prev = __hip_atomic_fetch_add(
            bar + grp * 64, 1u, __ATOMIC_RELAXED, __HIP_MEMORY_SCOPE_AGENT);
        if ((prev & 15u) == 15u) {  // last of group (monotonic count)
          unsigned mprev = __hip_atomic_fetch_add(
              bar + 16 * 64, 1u, __ATOMIC_RELAXED, __HIP_MEMORY_SCOPE_AGENT);
          if ((mprev & 15u) == 15u) {  // last group: release everyone
#pragma unroll
            for (int g2 = 0; g2 < 16; ++g2)
              __hip_atomic_store(bar + (17 + g2) * 64, bar_gen,
                                 __ATOMIC_RELAXED, __HIP_MEMORY_SCOPE_AGENT);
          }
        }
      }
    }
  };
  auto bar_wait = [&]() {
    if (tid == 0) {
      if (__hip_atomic_load(bar + 33 * 64, __ATOMIC_RELAXED,
                            __HIP_MEMORY_SCOPE_AGENT) == 0u) {
        const unsigned grp = (unsigned)wg & 15u;
        unsigned spin = 0;
        while (__hip_atomic_load(bar + (17 + grp) * 64, __ATOMIC_RELAXED,
                                 __HIP_MEMORY_SCOPE_AGENT) < bar_gen) {
          __builtin_amdgcn_s_sleep(1);
          if ((++spin & 255u) == 0u) {
            if (__hip_atomic_load(bar + 33 * 64, __ATOMIC_RELAXED,
                                  __HIP_MEMORY_SCOPE_AGENT) != 0u)
              break;
            if (spin > (1u << 19)) {  // failsafe: fast-fail, don't hang
              __hip_atomic_store(bar + 33 * 64, 1u, __ATOMIC_RELAXED,
                                 __HIP_MEMORY_SCOPE_AGENT);
              break;
            }
          }
        }
      }
    }
    __syncthreads();
    // R9: NO per-tick cache maintenance. Staleness is fully covered by the
    // 7-periodic agent fence (reuse distance 8 for L1 and L2 alike).
    // Compiler-only fence: forbid hoisting subsequent loads above the wait.
    asm volatile("" ::: "memory");
  };

  // ---- gates gemv: 16 rows x 64 b, K=1024 = [lo(512);hi(512)], k-major.
  //      Weights from LDS; activations via plain cached loads (true L2
  //      broadcast: zero per-tick invalidation). ----
  auto gemv = [&](const float* __restrict__ lo, const float* __restrict__ hi) {
    const int s = tid >> 3;  // k-slice 0..63
    const int tb = tid & 7;  // batch octet
    const int abase = s * 64 + tb * 8;
    float acc[128];
#pragma unroll
    for (int q = 0; q < 128; ++q) acc[q] = 0.f;

    f32x4 a_cur[4][2], a_nxt[4][2];
#pragma unroll
    for (int c = 0; c < 4; ++c) {
      const float* p = lo + c * 4096 + abase;
      a_cur[c][0] = *reinterpret_cast<const f32x4*>(p);
      a_cur[c][1] = *reinterpret_cast<const f32x4*>(p + 4);
    }
#pragma unroll
    for (int g = 0; g < 4; ++g) {
      if (g < 3) {
#pragma unroll
        for (int cc = 0; cc < 4; ++cc) {
          const int c = (g + 1) * 4 + cc;
          const float* p =
              (c < 8 ? lo + c * 4096 : hi + (c - 8) * 4096) + abase;
          a_nxt[cc][0] = *reinterpret_cast<const f32x4*>(p);
          a_nxt[cc][1] = *reinterpret_cast<const f32x4*>(p + 4);
        }
      }
      // rows in two halves of 8 to cap live wr[] registers
#pragma unroll
      for (int rh = 0; rh < 2; ++rh) {
        float4 wr[8];
#pragma unroll
        for (int r8 = 0; r8 < 8; ++r8)
          wr[r8] = *reinterpret_cast<const float4*>(
              &s_w[((rh * 8 + r8) * 64 + s) * P + g * 4]);
#pragma unroll
        for (int cc = 0; cc < 4; ++cc) {
          float av[8] = {a_cur[cc][0].x, a_cur[cc][0].y, a_cur[cc][0].z,
                         a_cur[cc][0].w, a_cur[cc][1].x, a_cur[cc][1].y,
                         a_cur[cc][1].z, a_cur[cc][1].w};
#pragma unroll
          for (int r8 = 0; r8 < 8; ++r8) {
            float w = (cc == 0)   ? wr[r8].x
                      : (cc == 1) ? wr[r8].y
                      : (cc == 2) ? wr[r8].z
                                  : wr[r8].w;
#pragma unroll
            for (int bb = 0; bb < 8; ++bb)
              acc[(rh * 8 + r8) * 8 + bb] =
                  fmaf(w, av[bb], acc[(rh * 8 + r8) * 8 + bb]);
          }
        }
      }
      if (g < 3) {
#pragma unroll
        for (int cc = 0; cc < 4; ++cc) {
          a_cur[cc][0] = a_nxt[cc][0];
          a_cur[cc][1] = a_nxt[cc][1];
        }
      }
    }

    // ---- exchange-and-halve reduction over lane bits 3..5 ----
    const int lane = tid & 63;
    const bool b3 = (lane & 8) != 0;
    const bool b4 = (lane & 16) != 0;
    const bool b5 = (lane & 32) != 0;
    float v1[64];
#pragma unroll
    for (int go = 0; go < 8; ++go)
#pragma unroll
      for (int j = 0; j < 8; ++j) {
        float lc = acc[(2 * go + 0) * 8 + j];
        float hc = acc[(2 * go + 1) * 8 + j];
        float lo_o = __shfl_xor(lc, 8, 64);
        float hi_o = __shfl_xor(hc, 8, 64);
        v1[go * 8 + j] = b3 ? (hc + hi_o) : (lc + lo_o);
      }
    float v2[32];
#pragma unroll
    for (int go = 0; go < 4; ++go)
#pragma unroll
      for (int j = 0; j < 8; ++j) {
        float lc = v1[(2 * go + 0) * 8 + j];
        float hc = v1[(2 * go + 1) * 8 + j];
        float lo_o = __shfl_xor(lc, 16, 64);
        float hi_o = __shfl_xor(hc, 16, 64);
        v2[go * 8 + j] = b4 ? (hc + hi_o) : (lc + lo_o);
      }
    float fin[16];
#pragma unroll
    for (int go = 0; go < 2; ++go)
#pragma unroll
      for (int j = 0; j < 8; ++j) {
        float lc = v2[(2 * go + 0) * 8 + j];
        float hc = v2[(2 * go + 1) * 8 + j];
        float lo_o = __shfl_xor(lc, 32, 64);
        float hi_o = __shfl_xor(hc, 32, 64);
        fin[go * 8 + j] = b5 ? (hc + hi_o) : (lc + lo_o);
      }
    // lane holds rows {sigma, 8+sigma} for b = tb*8 + j
    const int wv = tid >> 6;
    const int sigma = (lane >> 3) & 7;
    float* dst0 = s_red + wv * 1024 + sigma * 64 + tb * 8;
    *reinterpret_cast<float4*>(dst0) =
        make_float4(fin[0], fin[1], fin[2], fin[3]);
    *reinterpret_cast<float4*>(dst0 + 4) =
        make_float4(fin[4], fin[5], fin[6], fin[7]);
    float* dst1 = dst0 + 512;  // rows 8+sigma
    *reinterpret_cast<float4*>(dst1) =
        make_float4(fin[8], fin[9], fin[10], fin[11]);
    *reinterpret_cast<float4*>(dst1 + 4) =
        make_float4(fin[12], fin[13], fin[14], fin[15]);
    __syncthreads();
    {
      const float* bsum_l = ws + OFF_BSUM + layer * 2048;
#pragma unroll
      for (int h2 = 0; h2 < 2; ++h2) {
        int o = h2 * 512 + tid;
        float sum = 0.f;
#pragma unroll
        for (int w8 = 0; w8 < 8; ++w8) sum += s_red[w8 * 1024 + o];
        int r = o >> 6;
        int grow = (r >> 2) * 512 + lid * 4 + (r & 3);
        s_g[o] = sum + bsum_l[grow];  // s_g[r*64 + b]
      }
    }
    __syncthreads();
  };

  float cs = 0.f;  // tid<256 owns cell state (col = lid*4 + (tid>>6), b)

  auto cell_update = [&](float* dst) {
    if (tid < 256) {
      const int j = tid >> 6, b = tid & 63, col = lid * 4 + j;
      float ig = sigm(s_g[j * 64 + b]);
      float fg = sigm(s_g[(4 + j) * 64 + b]);
      float gt = tanh_fast(s_g[(8 + j) * 64 + b]);
      float og = sigm(s_g[(12 + j) * 64 + b]);
      cs = fg * cs + ig * gt;
      coh_store1(dst + col * 64 + b, og * tanh_fast(cs));
    }
  };

  // ---- inp(tn) = sigmoid(x[tn] @ w_in^T + b_in) -> cols lid*4..+3 ----
  auto inp_block = [&](int tn, int slot) {
    const int b = tid & 63, jj = (tid >> 6) & 3, kh = tid >> 8;
    const int col = lid * 4 + jj;
    const float* xsrc = x + ((size_t)tn * B + b) * I_DIM + kh * 64;
    const float* wrow = w_in + (size_t)col * I_DIM + kh * 64;
    float part = 0.f;
#pragma unroll
    for (int k4 = 0; k4 < 16; ++k4) {
      float4 xv = *reinterpret_cast<const float4*>(xsrc + k4 * 4);
      float4 wv = *reinterpret_cast<const float4*>(wrow + k4 * 4);
      part += xv.x * wv.x + xv.y * wv.y + xv.z * wv.z + xv.w * wv.w;
    }
    s_red[tid] = part;
    __syncthreads();
    if (tid < 256) {
      float v = s_red[tid] + s_red[tid + 256];
      const int jj2 = (tid >> 6) & 3, b2 = tid & 63;
      const int col2 = lid * 4 + jj2;
      coh_store1(ws + OFF_INP + (size_t)slot * HB + col2 * 64 + b2,
                 sigm(v + b_in[col2]));
    }
    __syncthreads();
  };

  // ---- out(tt): gather h1 column b into LDS once, then reduce ----
  auto out_block = [&](int tt, int slot) {
    const int b = lid >> 1, ihalf = lid & 1;
    s_h1[tid] = ws[OFF_H1 + (size_t)slot * HB + tid * 64 + b];  // cached
    __syncthreads();
    const int io = tid & 63, ks = tid >> 6;  // ks 0..7, 64 k each
    const int i = ihalf * 64 + io;
    const float* wrow = w_out + (size_t)i * H + ks * 64;
    const float* hl = s_h1 + ks * 64;  // broadcast across io lanes
    float part = 0.f;
#pragma unroll
    for (int k4 = 0; k4 < 16; ++k4) {
      float4 wv = *reinterpret_cast<const float4*>(wrow + k4 * 4);
      part += wv.x * hl[k4 * 4 + 0] + wv.y * hl[k4 * 4 + 1] +
              wv.z * hl[k4 * 4 + 2] + wv.w * hl[k4 * 4 + 3];
    }
    s_red[tid] = part;
    __syncthreads();
    if (tid < 64) {
      float sum = 0.f;
#pragma unroll
      for (int kk = 0; kk < 8; ++kk) sum += s_red[kk * 64 + tid];
      const int ii = ihalf * 64 + tid;
      coh_store1(out + ((size_t)tt * B + b) * I_DIM + ii, sum + b_out[ii]);
    }
    __syncthreads();
  };

  // ---------------- prologue: inp(0), inp(1); barrier B0 (inv) ----------
  if (layer == 0) {
    inp_block(0, 0);
    inp_block(1, 1);
  }
  bar_arrive(true);  // B0: k=0 -> inv barrier (also kills pre-launch lines)
  bar_wait();

  // ---------------- pipelined main loop: one barrier per tick -----------
  // tick tau: L0 computes h0(tau); L1 computes h1(tau-1). Window work
  // (between arrive and wait): L0 writes inp(tau+2), L1 writes out(tau-2).
  // Barrier after tick tau is B_{tau+1}; inv when (tau+1)%7==0.
  for (int tau = 0; tau <= T_STEPS + 1; ++tau) {
    const int sl = tau & 7;
    const float* glo;
    const float* ghi;
    float* gdst;
    bool do_g;
    if (layer == 0) {
      glo = ws + OFF_INP + (size_t)sl * HB;                  // inp(tau)
      ghi = ws + OFF_H0 + (size_t)((tau - 1) & 7) * HB;      // h0(tau-1)
      gdst = ws + OFF_H0 + (size_t)sl * HB;                  // h0(tau)
      do_g = (tau < T_STEPS);
    } else {
      glo = ws + OFF_H0 + (size_t)((tau - 1) & 7) * HB;      // h0(tau-1)
      ghi = ws + OFF_H1 + (size_t)((tau - 2) & 7) * HB;      // h1(tau-2)
      gdst = ws + OFF_H1 + (size_t)((tau - 1) & 7) * HB;     // h1(tau-1)
      do_g = (tau >= 1 && tau <= T_STEPS);
    }
    if (do_g) {
      gemv(glo, ghi);
      cell_update(gdst);
    }
    if (tau <= T_STEPS) {
      bar_arrive(((tau + 1) % 7) == 0);
      // ---- window work (post-arrival, pre-release) ----
      if (layer == 0) {
        if (tau + 2 <= T_STEPS - 1) inp_block(tau + 2, (tau + 2) & 7);
      } else {
        if (tau >= 2) out_block(tau - 2, (tau - 2) & 7);
      }
      bar_wait();
    } else {
      // final tick (tau == T_STEPS+1): no barrier; L1 emits last output
      if (layer == 1) out_block(tau - 2, (tau - 2) & 7);
    }
  }
}

extern "C" void kernel_launch(void* const* d_in, const int* in_sizes, int n_in,
                              void* d_out, int out_size, void* d_ws,
                              size_t ws_size, hipStream_t stream) {
  const float* x     = (const float*)d_in[0];
  const float* w_in  = (const float*)d_in[1];
  const float* b_in  = (const float*)d_in[2];
  const float* w_ih  = (const float*)d_in[3];
  const float* w_hh  = (const float*)d_in[4];
  const float* b_ih  = (const float*)d_in[5];
  const float* b_hh  = (const float*)d_in[6];
  const float* w_out = (const float*)d_in[7];
  const float* b_out = (const float*)d_in[8];
  float* ws   = (float*)d_ws;
  float* outp = (float*)d_out;

  hipLaunchKernelGGL(init_ws_kernel, dim3(NBLK), dim3(NTHR), 0, stream, ws,
                     b_ih, b_hh);
  hipLaunchKernelGGL(lstm_kernel, dim3(NBLK), dim3(NTHR), 0, stream, x, w_in,
                     b_in, w_ih, w_hh, w_out, b_out, ws, outp);
}